// Round 3
// baseline (46.362 us; speedup 1.0000x reference)
//
#include <hip/hip_runtime.h>

// out[b,t,h,d] = cos(x[b,t,h,d] + sum_j theta[h,j])
// B=64, T=8192, H=8, HD=8 -> 33,554,432 f32 elements. Memory-bound streaming op.
// Round 2: same as round 1 but with Clang ext-vector float4 so
// __builtin_nontemporal_store compiles (HIP_vector_type is a class, rejected).

typedef float f32x4 __attribute__((ext_vector_type(4)));

__global__ __launch_bounds__(256) void mhaq_cos_kernel(
    const float* __restrict__ x,
    const float* __restrict__ theta,
    float* __restrict__ out,
    long long n4)
{
    // Per-head total phase: phase[h] = sum_{j<8} theta[h*8+j]. 64 floats, L1-resident.
    __shared__ float s_phase[8];
    if (threadIdx.x < 8) {
        float p = 0.0f;
        #pragma unroll
        for (int j = 0; j < 8; ++j) p += theta[threadIdx.x * 8 + j];
        s_phase[threadIdx.x] = p;
    }
    __syncthreads();

    const f32x4* __restrict__ x4 = reinterpret_cast<const f32x4*>(x);
    f32x4* __restrict__ o4 = reinterpret_cast<f32x4*>(out);

    const float inv2pi = 0.15915494309189535f; // 1/(2*pi)

    const long long tid    = (long long)blockIdx.x * blockDim.x + threadIdx.x;
    const long long stride = (long long)gridDim.x * blockDim.x;

    // stride is a multiple of 16 (2048*256), so (i & 15) is invariant across the
    // grid-stride loop: head index, and therefore the phase, is per-thread constant.
    // float4 chunk -> element col = 4*i & 63 -> head = ((i & 15) >> 1).
    const float ph = s_phase[(int)((tid & 15) >> 1)];

    auto body = [&](f32x4 v) -> f32x4 {
        f32x4 r;
        // v_cos_f32 takes revolutions; fract() is the exact 2π-periodic reduction.
        r.x = __builtin_amdgcn_cosf(__builtin_amdgcn_fractf((v.x + ph) * inv2pi));
        r.y = __builtin_amdgcn_cosf(__builtin_amdgcn_fractf((v.y + ph) * inv2pi));
        r.z = __builtin_amdgcn_cosf(__builtin_amdgcn_fractf((v.z + ph) * inv2pi));
        r.w = __builtin_amdgcn_cosf(__builtin_amdgcn_fractf((v.w + ph) * inv2pi));
        return r;
    };

    long long i = tid;
    // 4-deep batch: 4 independent loads in flight before any store.
    for (; i + 3 * stride < n4; i += 4 * stride) {
        f32x4 v0 = x4[i];
        f32x4 v1 = x4[i + stride];
        f32x4 v2 = x4[i + 2 * stride];
        f32x4 v3 = x4[i + 3 * stride];
        f32x4 r0 = body(v0);
        f32x4 r1 = body(v1);
        f32x4 r2 = body(v2);
        f32x4 r3 = body(v3);
        // Non-temporal: output is never re-read; keep it from evicting x in L2/L3.
        __builtin_nontemporal_store(r0, &o4[i]);
        __builtin_nontemporal_store(r1, &o4[i + stride]);
        __builtin_nontemporal_store(r2, &o4[i + 2 * stride]);
        __builtin_nontemporal_store(r3, &o4[i + 3 * stride]);
    }
    for (; i < n4; i += stride) {
        __builtin_nontemporal_store(body(x4[i]), &o4[i]);
    }
}

extern "C" void kernel_launch(void* const* d_in, const int* in_sizes, int n_in,
                              void* d_out, int out_size, void* d_ws, size_t ws_size,
                              hipStream_t stream) {
    const float* x     = (const float*)d_in[0];   // [B,T,H*HD] f32
    const float* theta = (const float*)d_in[1];   // [H,HD] f32
    float* out         = (float*)d_out;           // [B,T,H*HD] f32

    long long n  = (long long)out_size;           // 33,554,432 (divisible by 4)
    long long n4 = n >> 2;

    const int block = 256;
    const int grid  = 2048; // 256 CUs x 8 blocks/CU; stride = 524288 (mult of 16)

    mhaq_cos_kernel<<<grid, block, 0, stream>>>(x, theta, out, n4);
}

// Round 4
// 45.899 us; speedup vs baseline: 1.0101x; 1.0101x over previous
//
#include <hip/hip_runtime.h>

// out[b,t,h,d] = cos(x[b,t,h,d] + sum_j theta[h,j])
// B=64, T=8192, H=8, HD=8 -> 33,554,432 f32 elements. Memory-bound streaming op.
// Round 3: revert round-2's 4-deep batching (VGPR 8->32 cost occupancy 70%->52%,
// net regression). Keep: ext-vector float4, NT stores, hoisted per-thread phase.

typedef float f32x4 __attribute__((ext_vector_type(4)));

__global__ __launch_bounds__(256) void mhaq_cos_kernel(
    const float* __restrict__ x,
    const float* __restrict__ theta,
    float* __restrict__ out,
    long long n4)
{
    // Per-head total phase: phase[h] = sum_{j<8} theta[h*8+j]. 64 floats, L1-resident.
    __shared__ float s_phase[8];
    if (threadIdx.x < 8) {
        float p = 0.0f;
        #pragma unroll
        for (int j = 0; j < 8; ++j) p += theta[threadIdx.x * 8 + j];
        s_phase[threadIdx.x] = p;
    }
    __syncthreads();

    const f32x4* __restrict__ x4 = reinterpret_cast<const f32x4*>(x);
    f32x4* __restrict__ o4 = reinterpret_cast<f32x4*>(out);

    const float inv2pi = 0.15915494309189535f; // 1/(2*pi)

    const long long tid    = (long long)blockIdx.x * blockDim.x + threadIdx.x;
    const long long stride = (long long)gridDim.x * blockDim.x;

    // stride = 2048*256 = 524288, a multiple of 16, so (i & 15) — and therefore the
    // head index and phase — is invariant across the grid-stride loop per thread.
    // float4 chunk i -> element col = (4*i) & 63 -> head = ((i & 15) >> 1).
    const float ph = s_phase[(int)((tid & 15) >> 1)];

    for (long long i = tid; i < n4; i += stride) {
        f32x4 v = x4[i];
        f32x4 r;
        // v_cos_f32 takes revolutions; fract() is the exact 2π-periodic reduction.
        r.x = __builtin_amdgcn_cosf(__builtin_amdgcn_fractf((v.x + ph) * inv2pi));
        r.y = __builtin_amdgcn_cosf(__builtin_amdgcn_fractf((v.y + ph) * inv2pi));
        r.z = __builtin_amdgcn_cosf(__builtin_amdgcn_fractf((v.z + ph) * inv2pi));
        r.w = __builtin_amdgcn_cosf(__builtin_amdgcn_fractf((v.w + ph) * inv2pi));
        // NT store: output is never re-read by this kernel; no reason to cache it
        // preferentially. (Measured round 2: neutral on FETCH, keep for hygiene.)
        __builtin_nontemporal_store(r, &o4[i]);
    }
}

extern "C" void kernel_launch(void* const* d_in, const int* in_sizes, int n_in,
                              void* d_out, int out_size, void* d_ws, size_t ws_size,
                              hipStream_t stream) {
    const float* x     = (const float*)d_in[0];   // [B,T,H*HD] f32
    const float* theta = (const float*)d_in[1];   // [H,HD] f32
    float* out         = (float*)d_out;           // [B,T,H*HD] f32

    long long n  = (long long)out_size;           // 33,554,432 (divisible by 4)
    long long n4 = n >> 2;

    const int block = 256;
    const int grid  = 2048; // 8 blocks/CU x 256 CUs; stride multiple of 16

    mhaq_cos_kernel<<<grid, block, 0, stream>>>(x, theta, out, n4);
}

// Round 5
// 42.456 us; speedup vs baseline: 1.0920x; 1.0811x over previous
//
#include <hip/hip_runtime.h>

// out[b,t,h,d] = cos(x[b,t,h,d] + sum_j theta[h,j])
// B=64, T=8192, H=8, HD=8 -> 33,554,432 f32 elements. Memory-bound streaming op.
// Round 4: flat launch — one float4 per thread, no grid-stride loop. Mimics the
// D2D-copy structure (6.29 TB/s ceiling); removes per-thread serial chain of 16
// load->cos->store iterations. Keep NT store, ext-vector float4, LDS phase.

typedef float f32x4 __attribute__((ext_vector_type(4)));

__global__ __launch_bounds__(256) void mhaq_cos_kernel(
    const float* __restrict__ x,
    const float* __restrict__ theta,
    float* __restrict__ out,
    long long n4)
{
    __shared__ float s_phase[8];
    if (threadIdx.x < 8) {
        float p = 0.0f;
        #pragma unroll
        for (int j = 0; j < 8; ++j) p += theta[threadIdx.x * 8 + j];
        s_phase[threadIdx.x] = p;
    }
    __syncthreads();

    const long long i = (long long)blockIdx.x * blockDim.x + threadIdx.x;
    if (i >= n4) return;

    // float4 chunk i -> element col = (4*i) & 63 -> head = ((i & 15) >> 1).
    const float ph = s_phase[(int)((i & 15) >> 1)];
    const float inv2pi = 0.15915494309189535f; // 1/(2*pi)

    const f32x4* __restrict__ x4 = reinterpret_cast<const f32x4*>(x);
    f32x4* __restrict__ o4 = reinterpret_cast<f32x4*>(out);

    f32x4 v = x4[i];
    f32x4 r;
    // v_cos_f32 takes revolutions; fract() is the exact 2π-periodic reduction.
    r.x = __builtin_amdgcn_cosf(__builtin_amdgcn_fractf((v.x + ph) * inv2pi));
    r.y = __builtin_amdgcn_cosf(__builtin_amdgcn_fractf((v.y + ph) * inv2pi));
    r.z = __builtin_amdgcn_cosf(__builtin_amdgcn_fractf((v.z + ph) * inv2pi));
    r.w = __builtin_amdgcn_cosf(__builtin_amdgcn_fractf((v.w + ph) * inv2pi));
    __builtin_nontemporal_store(r, &o4[i]);
}

extern "C" void kernel_launch(void* const* d_in, const int* in_sizes, int n_in,
                              void* d_out, int out_size, void* d_ws, size_t ws_size,
                              hipStream_t stream) {
    const float* x     = (const float*)d_in[0];   // [B,T,H*HD] f32
    const float* theta = (const float*)d_in[1];   // [H,HD] f32
    float* out         = (float*)d_out;           // [B,T,H*HD] f32

    long long n  = (long long)out_size;           // 33,554,432 (divisible by 4)
    long long n4 = n >> 2;                        // 8,388,608 float4 chunks

    const int block = 256;
    const int grid  = (int)((n4 + block - 1) / block); // 32768 blocks, flat

    mhaq_cos_kernel<<<grid, block, 0, stream>>>(x, theta, out, n4);
}